// Round 1
// baseline (236.819 us; speedup 1.0000x reference)
//
#include <hip/hip_runtime.h>

typedef __attribute__((ext_vector_type(4))) _Float16 f16x4;
typedef __attribute__((ext_vector_type(4))) float f32x4;

#define NB 4096
#define TT 200
#define DD 64
#define H0 128
#define H1 64
#define TPAD 208
#define NSTRIP 13

// Per-block (one history b): fold the DIN feature concat into a per-b 64x128
// matrix M_b = W0b - W0c + diag(q) W0d and bias c_b = b0 + q@(W0a + W0c).
// Layer0/Layer1 run as fp16 MFMA GEMMs with hi/lo activation-split error
// compensation (2 MFMAs per k-step); logits/softmax/pooling in fp32.
__global__ __launch_bounds__(256, 2)
void din_attn(const float* __restrict__ q, const float* __restrict__ k,
              const float* __restrict__ v, const int* __restrict__ mask,
              const float* __restrict__ W0, const float* __restrict__ b0,
              const float* __restrict__ W1, const float* __restrict__ b1,
              const float* __restrict__ Wf, float* __restrict__ out)
{
  const int b    = blockIdx.x;
  const int tid  = threadIdx.x;
  const int lane = tid & 63;
  const int wid  = tid >> 6;
  const int r16  = lane & 15;   // A-row / B-col / D-col index
  const int g4   = lane >> 4;   // k-group / D row-group

  __shared__ __align__(16) _Float16 MhT[H0 * 72];    // [h][d], pad 72
  __shared__ __align__(16) _Float16 W1T[H1 * 136];   // [j][h], pad 136
  __shared__ float cb[H0];
  __shared__ float msk[TPAD];                        // 1 keep, 0 masked, -1 pad
  __shared__ __align__(16) float h0s[4][16 * 132];   // per-wave H0 strip scratch
  __shared__ float owav[4][68];
  __shared__ float msh[4];
  __shared__ float ssh[4];

  const float* qb = q + b * DD;
  const float* kb = k + (size_t)b * TT * DD;
  const float* vb = v + (size_t)b * TT * DD;

  // ---- staging ----
  for (int t = tid; t < TPAD; t += 256)
    msk[t] = (t < TT) ? (mask[b * TT + t] ? 1.f : 0.f) : -1.f;

  if (tid < H0) {
    float s = b0[tid];
    #pragma unroll 8
    for (int d = 0; d < DD; ++d)
      s += qb[d] * (W0[d * H0 + tid] + W0[(128 + d) * H0 + tid]);
    cb[tid] = s;
  }

  #pragma unroll 4
  for (int i = 0; i < 32; ++i) {            // M_b transposed -> LDS (fp16)
    int idx = i * 256 + tid;
    int h = idx & 127, d = idx >> 7;
    float val = W0[(64 + d) * H0 + h] - W0[(128 + d) * H0 + h]
              + qb[d] * W0[(192 + d) * H0 + h];
    MhT[h * 72 + d] = (_Float16)val;
  }

  #pragma unroll 4
  for (int i = 0; i < 32; ++i) {            // W1 transposed -> LDS (fp16)
    int idx = i * 256 + tid;
    int hh = idx >> 6, j = idx & 63;
    W1T[j * 136 + hh] = (_Float16)W1[idx];
  }

  __syncthreads();

  float b1v[4], wfv[4];
  #pragma unroll
  for (int c = 0; c < 4; ++c) {
    b1v[c] = b1[c * 16 + r16];
    wfv[c] = Wf[c * 16 + r16];
  }

  // per-wave online-softmax state (d = lane for the pooled accumulator)
  float m_run = -1e30f, s_run = 0.f, o_run = 0.f;
  float* hsrow = h0s[wid];

  for (int s = wid; s < NSTRIP; s += 4) {
    const int t0 = s * 16;
    const int trow = t0 + r16;

    // k A-fragments straight from global (fp32), v stream issued early
    float4 kq[4];
    #pragma unroll
    for (int ks = 0; ks < 4; ++ks) {
      float4 z; z.x = z.y = z.z = z.w = 0.f;
      kq[ks] = (trow < TT) ? *(const float4*)(kb + trow * DD + ks * 16 + 4 * g4) : z;
    }
    float vv[16];
    #pragma unroll
    for (int i = 0; i < 16; ++i) {
      int t = t0 + i;
      vv[i] = (t < TT) ? vb[t * DD + lane] : 0.f;
    }

    // split k into hi/lo fp16 fragments
    f16x4 ahi[4], alo[4];
    #pragma unroll
    for (int ks = 0; ks < 4; ++ks) {
      float kf[4] = {kq[ks].x, kq[ks].y, kq[ks].z, kq[ks].w};
      #pragma unroll
      for (int j = 0; j < 4; ++j) {
        _Float16 hi = (_Float16)kf[j];
        ahi[ks][j] = hi;
        alo[ks][j] = (_Float16)(kf[j] - (float)hi);
      }
    }

    // ---- layer0: H0[16x128] = relu(k @ M_b + c_b) ----
    #pragma unroll
    for (int c = 0; c < 8; ++c) {
      f32x4 acc = {0.f, 0.f, 0.f, 0.f};
      #pragma unroll
      for (int ks = 0; ks < 4; ++ks) {
        f16x4 bf = *(const f16x4*)(&MhT[(c * 16 + r16) * 72 + ks * 16 + 4 * g4]);
        acc = __builtin_amdgcn_mfma_f32_16x16x16f16(ahi[ks], bf, acc, 0, 0, 0);
        acc = __builtin_amdgcn_mfma_f32_16x16x16f16(alo[ks], bf, acc, 0, 0, 0);
      }
      float cbv = cb[c * 16 + r16];
      #pragma unroll
      for (int r = 0; r < 4; ++r) {
        float h0v = acc[r] + cbv;
        h0v = h0v > 0.f ? h0v : 0.f;
        hsrow[(g4 * 4 + r) * 132 + c * 16 + r16] = h0v;
      }
    }

    // ---- layer1 A-fragments from scratch, hi/lo split ----
    f16x4 hhi[8], hlo[8];
    #pragma unroll
    for (int ks = 0; ks < 8; ++ks) {
      f32x4 hv = *(const f32x4*)(&hsrow[r16 * 132 + ks * 16 + 4 * g4]);
      #pragma unroll
      for (int j = 0; j < 4; ++j) {
        _Float16 hi = (_Float16)hv[j];
        hhi[ks][j] = hi;
        hlo[ks][j] = (_Float16)(hv[j] - (float)hi);
      }
    }

    // ---- layer1 + logit: h1 = relu(H0 @ W1 + b1); p = h1 . Wf ----
    float p[4] = {0.f, 0.f, 0.f, 0.f};
    #pragma unroll
    for (int c = 0; c < 4; ++c) {
      f32x4 acc = {0.f, 0.f, 0.f, 0.f};
      #pragma unroll
      for (int ks = 0; ks < 8; ++ks) {
        f16x4 bf = *(const f16x4*)(&W1T[(c * 16 + r16) * 136 + ks * 16 + 4 * g4]);
        acc = __builtin_amdgcn_mfma_f32_16x16x16f16(hhi[ks], bf, acc, 0, 0, 0);
        acc = __builtin_amdgcn_mfma_f32_16x16x16f16(hlo[ks], bf, acc, 0, 0, 0);
      }
      #pragma unroll
      for (int r = 0; r < 4; ++r) {
        float h1v = acc[r] + b1v[c];
        h1v = h1v > 0.f ? h1v : 0.f;
        p[r] = fmaf(h1v, wfv[c], p[r]);
      }
    }
    // reduce logit across the 16 lanes of each row-group
    #pragma unroll
    for (int mset = 1; mset < 16; mset <<= 1) {
      #pragma unroll
      for (int r = 0; r < 4; ++r)
        p[r] += __shfl_xor(p[r], mset, 64);
    }
    // mask: keep / masked(-1e30) / pad(-2e30)
    #pragma unroll
    for (int r = 0; r < 4; ++r) {
      float mm = msk[t0 + g4 * 4 + r];
      p[r] = (mm > 0.5f) ? p[r] : (mm < -0.5f ? -2e30f : -1e30f);
    }
    // gather all 16 strip logits to every lane
    float lt[16];
    #pragma unroll
    for (int g = 0; g < 4; ++g)
      #pragma unroll
      for (int r = 0; r < 4; ++r)
        lt[g * 4 + r] = __shfl(p[r], g * 16, 64);

    // online softmax update + v pooling
    float m_new = m_run;
    #pragma unroll
    for (int i = 0; i < 16; ++i) m_new = fmaxf(m_new, lt[i]);
    float scale = __expf(m_run - m_new);
    float e[16];
    float esum = 0.f;
    #pragma unroll
    for (int i = 0; i < 16; ++i) { e[i] = __expf(lt[i] - m_new); esum += e[i]; }
    s_run = s_run * scale + esum;
    o_run *= scale;
    #pragma unroll
    for (int i = 0; i < 16; ++i) o_run = fmaf(e[i], vv[i], o_run);
    m_run = m_new;
  }

  // ---- cross-wave flash combine ----
  owav[wid][lane] = o_run;
  if (lane == 0) { msh[wid] = m_run; ssh[wid] = s_run; }
  __syncthreads();

  if (tid < DD) {
    float mstar = fmaxf(fmaxf(msh[0], msh[1]), fmaxf(msh[2], msh[3]));
    float acc = 0.f, ssum = 0.f;
    #pragma unroll
    for (int w = 0; w < 4; ++w) {
      float f = __expf(msh[w] - mstar);
      acc  += owav[w][tid] * f;
      ssum += ssh[w] * f;
    }
    out[b * DD + tid] = acc / ssum;
  }
}

extern "C" void kernel_launch(void* const* d_in, const int* in_sizes, int n_in,
                              void* d_out, int out_size, void* d_ws, size_t ws_size,
                              hipStream_t stream) {
  const float* q    = (const float*)d_in[0];
  const float* k    = (const float*)d_in[1];
  const float* v    = (const float*)d_in[2];
  const int*   mask = (const int*)d_in[3];
  const float* W0   = (const float*)d_in[4];
  const float* b0   = (const float*)d_in[5];
  const float* W1   = (const float*)d_in[6];
  const float* b1   = (const float*)d_in[7];
  const float* Wf   = (const float*)d_in[8];
  float* out = (float*)d_out;
  din_attn<<<dim3(NB), dim3(256), 0, stream>>>(q, k, v, mask, W0, b0, W1, b1, Wf, out);
}